// Round 1
// baseline (9805.827 us; speedup 1.0000x reference)
//
#include <hip/hip_runtime.h>
#include <stdint.h>

// Problem constants
#define Bq   128
#define Tq   512
#define Fq   64
#define Hq   512
#define G4q  2048
#define FUTq 64

// Grid: 256 WGs = 8 row-groups (mg) x 32 unit-groups (ng), 256 thr (4 waves)
// Wave wv owns N-tile of 16 cols = 4 hidden units x 4 gates (packed),
// all waves share the WG's 16 batch rows (one 16-row M-tile).
// U is held in VGPRs as B-fragments (hi+lo bf16) for the whole kernel.

typedef __attribute__((ext_vector_type(8))) short bfrag_t;   // 8 bf16 = 1 MFMA A/B frag
typedef __attribute__((ext_vector_type(4))) float accf_t;    // MFMA C/D frag
typedef __attribute__((ext_vector_type(4))) float f4_t;

static __device__ __forceinline__ accf_t mfma16(uint4 a, uint4 b, accf_t acc) {
  return __builtin_amdgcn_mfma_f32_16x16x32_bf16(
      __builtin_bit_cast(bfrag_t, a), __builtin_bit_cast(bfrag_t, b), acc, 0, 0, 0);
}

// split f0,f1 (fp32) into packed bf16-hi word and bf16-lo (residual) word
static __device__ __forceinline__ void pack2(float f0, float f1, uint32_t& h, uint32_t& l) {
  uint32_t b0 = __float_as_uint(f0), b1 = __float_as_uint(f1);
  h = (b0 >> 16) | (b1 & 0xffff0000u);
  float r0 = f0 - __uint_as_float(b0 & 0xffff0000u);
  float r1 = f1 - __uint_as_float(b1 & 0xffff0000u);
  l = (__float_as_uint(r0) >> 16) | (__float_as_uint(r1) & 0xffff0000u);
}

static __device__ __forceinline__ float sigmoidf_(float v) {
  return __fdividef(1.0f, 1.0f + __expf(-v));
}

static __device__ __forceinline__ void waitge(uint32_t* p, uint32_t tgt) {
  int guard = 0;
  while (__hip_atomic_load(p, __ATOMIC_RELAXED, __HIP_MEMORY_SCOPE_AGENT) < tgt) {
    __builtin_amdgcn_s_sleep(1);
    if (++guard > (1 << 24)) break;  // hang-guard: fail loudly (wrong), never deadlock
  }
}

__global__ __launch_bounds__(256, 1) void lstm_persist(
    const float* __restrict__ x, const float* __restrict__ W,
    const float* __restrict__ U, const float* __restrict__ bias_v,
    const float* __restrict__ Wd, const float* __restrict__ bd,
    unsigned short* __restrict__ hbase,    // [4][128*512] : hi[p0],hi[p1],lo[p0],lo[p1]
    uint32_t* __restrict__ prod, uint32_t* __restrict__ rdone,
    float* __restrict__ out)
{
  const int wg  = blockIdx.x;
  const int mg  = wg >> 5;          // 0..7 : rows mg*16 .. +16
  const int ng  = wg & 31;          // 0..31: units ng*16 .. +16
  const int tid = threadIdx.x;
  const int wv  = tid >> 6;         // wave 0..3
  const int l   = tid & 63;
  const int c   = l & 15;           // MFMA col / A-row lane
  const int h4  = l >> 4;           // k-quadrant
  const int gate = c & 3;           // 0=i 1=f 2=g 3=o
  const int unit = ng * 16 + wv * 4 + (c >> 2);   // global hidden unit
  const int srccol = gate * 512 + unit;           // source column in U/W/b
  const size_t HOFF = (size_t)Bq * Hq;            // 65536 elems per h buffer

  __shared__ float lds[128][65];

  // ---------------- stage U into B-fragment registers (hi/lo bf16) -----------
  uint4 Bhi[16], Blo[16];
  const int srow = tid >> 2, sg = tid & 3;
  #pragma unroll
  for (int tb = 0; tb < 4; ++tb) {
    __syncthreads();
    #pragma unroll
    for (int p = 0; p < 2; ++p) {
      const int kl = p * 64 + srow;                       // 0..127
      const float* src = U + (size_t)(tb * 128 + kl) * G4q + sg * 512 + ng * 16;
      #pragma unroll
      for (int q = 0; q < 4; ++q) {
        f4_t vv = *(const f4_t*)(src + q * 4);
        #pragma unroll
        for (int e = 0; e < 4; ++e) {
          int uu = q * 4 + e;
          lds[kl][(uu >> 2) * 16 + (uu & 3) * 4 + sg] = vv[e];
        }
      }
    }
    __syncthreads();
    #pragma unroll
    for (int k2 = 0; k2 < 4; ++k2) {
      const int kk = tb * 4 + k2;
      uint32_t wh[4], wl[4];
      #pragma unroll
      for (int jp = 0; jp < 4; ++jp) {
        const int kloc = k2 * 32 + h4 * 8 + jp * 2;
        pack2(lds[kloc][wv * 16 + c], lds[kloc + 1][wv * 16 + c], wh[jp], wl[jp]);
      }
      Bhi[kk] = make_uint4(wh[0], wh[1], wh[2], wh[3]);
      Blo[kk] = make_uint4(wl[0], wl[1], wl[2], wl[3]);
    }
  }

  // ---------------- stage W (input kernel) the same way ----------------------
  uint4 Wh[2], Wl[2];
  __syncthreads();
  {
    const float* src = W + (size_t)srow * G4q + sg * 512 + ng * 16;
    #pragma unroll
    for (int q = 0; q < 4; ++q) {
      f4_t vv = *(const f4_t*)(src + q * 4);
      #pragma unroll
      for (int e = 0; e < 4; ++e) {
        int uu = q * 4 + e;
        lds[srow][(uu >> 2) * 16 + (uu & 3) * 4 + sg] = vv[e];
      }
    }
  }
  __syncthreads();
  #pragma unroll
  for (int kk = 0; kk < 2; ++kk) {
    uint32_t wh[4], wl[4];
    #pragma unroll
    for (int jp = 0; jp < 4; ++jp) {
      const int kloc = kk * 32 + h4 * 8 + jp * 2;
      pack2(lds[kloc][wv * 16 + c], lds[kloc + 1][wv * 16 + c], wh[jp], wl[jp]);
    }
    Wh[kk] = make_uint4(wh[0], wh[1], wh[2], wh[3]);
    Wl[kk] = make_uint4(wl[0], wl[1], wl[2], wl[3]);
  }

  const float bval = bias_v[srccol];
  float cst[4] = {0.f, 0.f, 0.f, 0.f};     // cell state: 4 rows x (this lane's unit)

  const float* xrow = x + (size_t)(mg * 16 + c) * Tq * Fq + h4 * 8;
  const size_t aoff = (size_t)(mg * 16 + c) * Hq + h4 * 8;   // A-frag elem offset
  const int fidx = mg * 32 + ng;

  // ---------------- recurrence ----------------------------------------------
  for (int t = 0; t < Tq; ++t) {
    const int pb = t & 1, pn = pb ^ 1;

    if (tid < 32)       waitge(&prod[mg * 32 + tid], (uint32_t)t);
    else if (tid < 64)  waitge(&rdone[mg * 32 + (tid - 32)], (uint32_t)t);
    __syncthreads();
    __builtin_amdgcn_fence(__ATOMIC_ACQUIRE, "agent");

    accf_t accA = {bval, bval, bval, bval};
    accf_t accB = {0.f, 0.f, 0.f, 0.f};
    accf_t accC = {0.f, 0.f, 0.f, 0.f};

    // x @ W contribution (K = 64)
    {
      const float* xp = xrow + (size_t)t * Fq;
      #pragma unroll
      for (int kk = 0; kk < 2; ++kk) {
        f4_t xa = *(const f4_t*)(xp + kk * 32);
        f4_t xb = *(const f4_t*)(xp + kk * 32 + 4);
        uint32_t xh[4], xl[4];
        pack2(xa[0], xa[1], xh[0], xl[0]);
        pack2(xa[2], xa[3], xh[1], xl[1]);
        pack2(xb[0], xb[1], xh[2], xl[2]);
        pack2(xb[2], xb[3], xh[3], xl[3]);
        uint4 XH = make_uint4(xh[0], xh[1], xh[2], xh[3]);
        uint4 XL = make_uint4(xl[0], xl[1], xl[2], xl[3]);
        accA = mfma16(XH, Wh[kk], accA);
        accB = mfma16(XL, Wh[kk], accB);
        accC = mfma16(XH, Wl[kk], accC);
      }
    }

    // h @ U contribution (K = 512), A-frags straight from global bf16 buffers
    {
      const uint4* ah = (const uint4*)(hbase + (size_t)pb * HOFF + aoff);
      const uint4* al = (const uint4*)(hbase + (size_t)(2 + pb) * HOFF + aoff);
      #pragma unroll
      for (int half = 0; half < 2; ++half) {
        uint4 Ah[8], Al[8];
        #pragma unroll
        for (int k8 = 0; k8 < 8; ++k8) {
          Ah[k8] = ah[(half * 8 + k8) * 4];
          Al[k8] = al[(half * 8 + k8) * 4];
        }
        #pragma unroll
        for (int k8 = 0; k8 < 8; ++k8) {
          const int kk = half * 8 + k8;
          accA = mfma16(Ah[k8], Bhi[kk], accA);
          accB = mfma16(Al[k8], Bhi[kk], accB);
          accC = mfma16(Ah[k8], Blo[kk], accC);
        }
      }
    }

    // gates + state update + h publish
    unsigned short* hw = hbase + (size_t)pn * HOFF;
    unsigned short* lw = hbase + (size_t)(2 + pn) * HOFF;
    #pragma unroll
    for (int r = 0; r < 4; ++r) {
      float zr = accA[r] + accB[r] + accC[r];
      float s1 = __shfl_xor(zr, 1);
      float s2 = __shfl_xor(zr, 2);
      float s3 = __shfl_xor(zr, 3);
      const bool b0 = (gate & 1), b1 = (gate & 2);
      float t01a = b0 ? s1 : zr, t23a = b0 ? s3 : s2;
      float iv = b1 ? t23a : t01a;
      float gv = b1 ? t01a : t23a;
      float t01b = b0 ? zr : s1, t23b = b0 ? s2 : s3;
      float fv = b1 ? t23b : t01b;
      float ov = b1 ? t01b : t23b;
      float si = sigmoidf_(iv);
      float sf = sigmoidf_(fv);
      float so = sigmoidf_(ov);
      float cn = sf * cst[r] + si * fmaxf(gv, 0.f);
      cst[r] = cn;
      float hn = so * fmaxf(cn, 0.f);

      uint32_t hb = __float_as_uint(hn);
      uint32_t hi16 = hb >> 16;
      float res = hn - __uint_as_float(hb & 0xffff0000u);
      uint32_t lo16 = __float_as_uint(res) >> 16;
      uint32_t hiw = hi16 | (((uint32_t)__shfl_xor((int)hi16, 4)) << 16);
      uint32_t low = lo16 | (((uint32_t)__shfl_xor((int)lo16, 4)) << 16);
      if (gate == 0 && (c & 4) == 0) {   // lanes holding even local unit: 4B stores
        const size_t off = (size_t)(mg * 16 + h4 * 4 + r) * Hq + unit;
        *(uint32_t*)(hw + off) = hiw;
        *(uint32_t*)(lw + off) = low;
      }
    }
    __syncthreads();
    if (tid == 0) {
      __hip_atomic_store(&rdone[fidx], (uint32_t)(t + 1), __ATOMIC_RELAXED, __HIP_MEMORY_SCOPE_AGENT);
      __hip_atomic_store(&prod[fidx], (uint32_t)(t + 1), __ATOMIC_RELEASE, __HIP_MEMORY_SCOPE_AGENT);
    }
  }

  // ---------------- final dense: y = h_last @ Wd + bd (exact fp32) ----------
  if (wg < 32) {
    const int mgy = wg >> 2;
    if (tid < 32) waitge(&prod[mgy * 32 + tid], (uint32_t)Tq);
    __syncthreads();
    __builtin_amdgcn_fence(__ATOMIC_ACQUIRE, "agent");
    const int r = tid >> 6;
    const int j = tid & 63;
    const int brow = wg * 4 + r;
    const unsigned short* hh = hbase + (size_t)brow * Hq;           // parity 0 = h_512
    const unsigned short* hl = hbase + 2 * HOFF + (size_t)brow * Hq;
    float acc = bd[j];
    #pragma unroll 8
    for (int k = 0; k < Hq; ++k) {
      float hv = __uint_as_float((uint32_t)hh[k] << 16) +
                 __uint_as_float((uint32_t)hl[k] << 16);
      acc = fmaf(hv, Wd[(size_t)k * FUTq + j], acc);
    }
    out[brow * FUTq + j] = acc;
  }
}

extern "C" void kernel_launch(void* const* d_in, const int* in_sizes, int n_in,
                              void* d_out, int out_size, void* d_ws, size_t ws_size,
                              hipStream_t stream) {
  (void)in_sizes; (void)n_in; (void)out_size; (void)ws_size;
  const float* x  = (const float*)d_in[0];
  const float* W  = (const float*)d_in[1];
  const float* U  = (const float*)d_in[2];
  const float* b  = (const float*)d_in[3];
  const float* Wd = (const float*)d_in[4];
  const float* bd = (const float*)d_in[5];

  unsigned short* hbase = (unsigned short*)d_ws;                    // 4 x 128KB
  uint32_t* prod  = (uint32_t*)((char*)d_ws + 512 * 1024);          // 256 x u32
  uint32_t* rdone = (uint32_t*)((char*)d_ws + 516 * 1024);          // 256 x u32

  // zero h parity-0 buffers (h_0 = 0) and all flags; ws is poisoned before each call
  hipMemsetAsync(d_ws, 0, 520 * 1024, stream);

  hipLaunchKernelGGL(lstm_persist, dim3(256), dim3(256), 0, stream,
                     x, W, U, b, Wd, bd, hbase, prod, rdone, (float*)d_out);
}

// Round 3
// 5313.271 us; speedup vs baseline: 1.8455x; 1.8455x over previous
//
#include <hip/hip_runtime.h>
#include <stdint.h>

// Problem constants
#define Bq   128
#define Tq   512
#define Fq   64
#define Hq   512
#define G4q  2048
#define FUTq 64

// 256 WGs = 8 row-groups (mg) x 32 unit-groups (ng), 256 thr (4 waves).
// Wave wv owns 16 z-cols = 4 hidden units x 4 gates; WG owns 16 batch rows.
// U resident in registers as hi/lo bf16 B-fragments.
// Cross-WG h exchange through the device coherence point (sc0 sc1 accesses),
// per-wave flags, NO cache-maintenance fences, NO barriers in the main loop.

typedef __attribute__((ext_vector_type(8))) short bfrag_t;
typedef __attribute__((ext_vector_type(4))) float accf_t;
typedef __attribute__((ext_vector_type(4))) float f4_t;

static __device__ __forceinline__ accf_t mfma16(uint4 a, uint4 b, accf_t acc) {
  return __builtin_amdgcn_mfma_f32_16x16x32_bf16(
      __builtin_bit_cast(bfrag_t, a), __builtin_bit_cast(bfrag_t, b), acc, 0, 0, 0);
}

static __device__ __forceinline__ void pack2(float f0, float f1, uint32_t& h, uint32_t& l) {
  uint32_t b0 = __float_as_uint(f0), b1 = __float_as_uint(f1);
  h = (b0 >> 16) | (b1 & 0xffff0000u);
  float r0 = f0 - __uint_as_float(b0 & 0xffff0000u);
  float r1 = f1 - __uint_as_float(b1 & 0xffff0000u);
  l = (__float_as_uint(r0) >> 16) | (__float_as_uint(r1) & 0xffff0000u);
}

static __device__ __forceinline__ float sigmoidf_(float v) {
  return __fdividef(1.0f, 1.0f + __expf(-v));
}

// coherence-point 16B load with compile-time byte offset
#define LD16(dst, base, IMM)                                                \
  asm volatile("global_load_dwordx4 %0, %1, off offset:" IMM " sc0 sc1"     \
               : "=v"(dst) : "v"(base) : "memory")

static __device__ __forceinline__ void st32_cc(void* p, uint32_t v) {
  asm volatile("global_store_dword %0, %1, off sc0 sc1" :: "v"(p), "v"(v) : "memory");
}
static __device__ __forceinline__ void stf_cc(void* p, float v) {
  asm volatile("global_store_dword %0, %1, off sc0 sc1" :: "v"(p), "v"(v) : "memory");
}
static __device__ __forceinline__ void wait_vm0() {
  asm volatile("s_waitcnt vmcnt(0)" ::: "memory");
  __builtin_amdgcn_sched_barrier(0);
}

static __device__ __forceinline__ void poll2(uint32_t* f0, uint32_t* f1, uint32_t tgt) {
  int guard = 0;
  for (;;) {
    uint32_t a = __hip_atomic_load(f0, __ATOMIC_RELAXED, __HIP_MEMORY_SCOPE_AGENT);
    uint32_t b = __hip_atomic_load(f1, __ATOMIC_RELAXED, __HIP_MEMORY_SCOPE_AGENT);
    if (a >= tgt && b >= tgt) return;
    __builtin_amdgcn_s_sleep(1);
    if (++guard > (1 << 23)) return;  // anti-hang; broken run fails validation
  }
}

__global__ __launch_bounds__(256, 1) void lstm_persist(
    const float* __restrict__ x, const float* __restrict__ W,
    const float* __restrict__ U, const float* __restrict__ bias_v,
    const float* __restrict__ Wd, const float* __restrict__ bd,
    unsigned short* __restrict__ hbase,   // [4][128*512]: hi[p0],hi[p1],lo[p0],lo[p1]
    uint32_t* __restrict__ prod2,         // [8][128] per-wave flags
    float* __restrict__ hfin,             // [128][512] final h fp32
    float* __restrict__ out)
{
  const int wg  = blockIdx.x;
  const int mg  = wg >> 5;
  const int ng  = wg & 31;
  const int tid = threadIdx.x;
  const int wv  = tid >> 6;
  const int l   = tid & 63;
  const int c   = l & 15;
  const int h4  = l >> 4;
  const int gate = c & 3;
  const int unit = ng * 16 + wv * 4 + (c >> 2);
  const int srccol = gate * 512 + unit;
  const size_t HOFF = (size_t)Bq * Hq;

  __shared__ float lds[128][65];

  // ---------------- stage U into B-fragment registers (hi/lo bf16) ----------
  uint4 Bhi[16], Blo[16];
  const int srow = tid >> 2, sg = tid & 3;
  #pragma unroll
  for (int tb = 0; tb < 4; ++tb) {
    __syncthreads();
    #pragma unroll
    for (int p = 0; p < 2; ++p) {
      const int kl = p * 64 + srow;
      const float* src = U + (size_t)(tb * 128 + kl) * G4q + sg * 512 + ng * 16;
      #pragma unroll
      for (int q = 0; q < 4; ++q) {
        f4_t vv = *(const f4_t*)(src + q * 4);
        #pragma unroll
        for (int e = 0; e < 4; ++e) {
          int uu = q * 4 + e;
          lds[kl][(uu >> 2) * 16 + (uu & 3) * 4 + sg] = vv[e];
        }
      }
    }
    __syncthreads();
    #pragma unroll
    for (int k2 = 0; k2 < 4; ++k2) {
      const int kk = tb * 4 + k2;
      uint32_t wh[4], wl[4];
      #pragma unroll
      for (int jp = 0; jp < 4; ++jp) {
        const int kloc = k2 * 32 + h4 * 8 + jp * 2;
        pack2(lds[kloc][wv * 16 + c], lds[kloc + 1][wv * 16 + c], wh[jp], wl[jp]);
      }
      Bhi[kk] = make_uint4(wh[0], wh[1], wh[2], wh[3]);
      Blo[kk] = make_uint4(wl[0], wl[1], wl[2], wl[3]);
    }
  }

  // ---------------- stage W the same way ------------------------------------
  uint4 Wh[2], Wl[2];
  __syncthreads();
  {
    const float* src = W + (size_t)srow * G4q + sg * 512 + ng * 16;
    #pragma unroll
    for (int q = 0; q < 4; ++q) {
      f4_t vv = *(const f4_t*)(src + q * 4);
      #pragma unroll
      for (int e = 0; e < 4; ++e) {
        int uu = q * 4 + e;
        lds[srow][(uu >> 2) * 16 + (uu & 3) * 4 + sg] = vv[e];
      }
    }
  }
  __syncthreads();
  #pragma unroll
  for (int kk = 0; kk < 2; ++kk) {
    uint32_t wh[4], wl[4];
    #pragma unroll
    for (int jp = 0; jp < 4; ++jp) {
      const int kloc = kk * 32 + h4 * 8 + jp * 2;
      pack2(lds[kloc][wv * 16 + c], lds[kloc + 1][wv * 16 + c], wh[jp], wl[jp]);
    }
    Wh[kk] = make_uint4(wh[0], wh[1], wh[2], wh[3]);
    Wl[kk] = make_uint4(wl[0], wl[1], wl[2], wl[3]);
  }
  __syncthreads();   // last LDS use until epilogue

  const float bval = bias_v[srccol];
  float cst[4] = {0.f, 0.f, 0.f, 0.f};

  const float* xrow = x + (size_t)(mg * 16 + c) * Tq * Fq + h4 * 8;
  const size_t aoff = (size_t)(mg * 16 + c) * Hq + h4 * 8;
  uint32_t* fb = prod2 + mg * 128;                 // row-group flag block
  const int fwv = mg * 128 + ng * 4 + wv;          // this wave's flag

  // ---------------- recurrence (no barriers, no fences) ---------------------
  for (int t = 0; t < Tq; ++t) {
    const int pb = t & 1, pn = pb ^ 1;

    // wait: all 128 producer-waves of this row-group finished step t-1
    poll2(fb + l, fb + 64 + l, (uint32_t)t);

    // issue all 32 h-loads (coherence-point reads)
    uint4 Ah[16], Al[16];
    const char* ap = (const char*)(hbase + (size_t)pb * HOFF + aoff);
    const char* lp = (const char*)(hbase + (size_t)(2 + pb) * HOFF + aoff);
    LD16(Ah[ 0], ap, "0");   LD16(Ah[ 1], ap, "64");  LD16(Ah[ 2], ap, "128"); LD16(Ah[ 3], ap, "192");
    LD16(Ah[ 4], ap, "256"); LD16(Ah[ 5], ap, "320"); LD16(Ah[ 6], ap, "384"); LD16(Ah[ 7], ap, "448");
    LD16(Ah[ 8], ap, "512"); LD16(Ah[ 9], ap, "576"); LD16(Ah[10], ap, "640"); LD16(Ah[11], ap, "704");
    LD16(Ah[12], ap, "768"); LD16(Ah[13], ap, "832"); LD16(Ah[14], ap, "896"); LD16(Ah[15], ap, "960");
    LD16(Al[ 0], lp, "0");   LD16(Al[ 1], lp, "64");  LD16(Al[ 2], lp, "128"); LD16(Al[ 3], lp, "192");
    LD16(Al[ 4], lp, "256"); LD16(Al[ 5], lp, "320"); LD16(Al[ 6], lp, "384"); LD16(Al[ 7], lp, "448");
    LD16(Al[ 8], lp, "512"); LD16(Al[ 9], lp, "576"); LD16(Al[10], lp, "640"); LD16(Al[11], lp, "704");
    LD16(Al[12], lp, "768"); LD16(Al[13], lp, "832"); LD16(Al[14], lp, "896"); LD16(Al[15], lp, "960");

    accf_t accA = {bval, bval, bval, bval};
    accf_t accB = {0.f, 0.f, 0.f, 0.f};
    accf_t accC = {0.f, 0.f, 0.f, 0.f};

    // x @ W under the h-load latency
    {
      const float* xp = xrow + (size_t)t * Fq;
      #pragma unroll
      for (int kk = 0; kk < 2; ++kk) {
        f4_t xa = *(const f4_t*)(xp + kk * 32);
        f4_t xb = *(const f4_t*)(xp + kk * 32 + 4);
        uint32_t xh[4], xl[4];
        pack2(xa[0], xa[1], xh[0], xl[0]);
        pack2(xa[2], xa[3], xh[1], xl[1]);
        pack2(xb[0], xb[1], xh[2], xl[2]);
        pack2(xb[2], xb[3], xh[3], xl[3]);
        uint4 XH = make_uint4(xh[0], xh[1], xh[2], xh[3]);
        uint4 XL = make_uint4(xl[0], xl[1], xl[2], xl[3]);
        accA = mfma16(XH, Wh[kk], accA);
        accB = mfma16(XL, Wh[kk], accB);
        accC = mfma16(XH, Wl[kk], accC);
      }
    }

    wait_vm0();   // h loads complete (+ sched_barrier, rule 18)

    #pragma unroll
    for (int kk = 0; kk < 16; ++kk) {
      accA = mfma16(Ah[kk], Bhi[kk], accA);
      accB = mfma16(Al[kk], Bhi[kk], accB);
      accC = mfma16(Ah[kk], Blo[kk], accC);
    }

    // gates + state update + publish h
    unsigned short* hw = hbase + (size_t)pn * HOFF;
    unsigned short* lw = hbase + (size_t)(2 + pn) * HOFF;
    #pragma unroll
    for (int r = 0; r < 4; ++r) {
      float zr = accA[r] + accB[r] + accC[r];
      float s1 = __shfl_xor(zr, 1);
      float s2 = __shfl_xor(zr, 2);
      float s3 = __shfl_xor(zr, 3);
      const bool b0 = (gate & 1), b1 = (gate & 2);
      float t01a = b0 ? s1 : zr, t23a = b0 ? s3 : s2;
      float iv = b1 ? t23a : t01a;
      float gv = b1 ? t01a : t23a;
      float t01b = b0 ? zr : s1, t23b = b0 ? s2 : s3;
      float fv = b1 ? t23b : t01b;
      float ov = b1 ? t01b : t23b;
      float si = sigmoidf_(iv);
      float sf = sigmoidf_(fv);
      float so = sigmoidf_(ov);
      float cn = sf * cst[r] + si * fmaxf(gv, 0.f);
      cst[r] = cn;
      float hn = so * fmaxf(cn, 0.f);

      uint32_t hb = __float_as_uint(hn);
      uint32_t hi16 = hb >> 16;
      float res = hn - __uint_as_float(hb & 0xffff0000u);
      uint32_t lo16 = __float_as_uint(res) >> 16;
      uint32_t hiw = hi16 | (((uint32_t)__shfl_xor((int)hi16, 4)) << 16);
      uint32_t low = lo16 | (((uint32_t)__shfl_xor((int)lo16, 4)) << 16);
      const int row = mg * 16 + h4 * 4 + r;
      if (gate == 0) {
        if ((c & 4) == 0) {
          const size_t off = (size_t)row * Hq + unit;
          st32_cc(hw + off, hiw);
          st32_cc(lw + off, low);
        }
        if (t == Tq - 1) stf_cc(hfin + (size_t)row * Hq + unit, hn);
      }
    }

    // order h-stores before flag, then publish per-wave flag
    asm volatile("s_waitcnt vmcnt(0)" ::: "memory");
    if (l == 0)
      __hip_atomic_store(&prod2[fwv], (uint32_t)(t + 1),
                         __ATOMIC_RELAXED, __HIP_MEMORY_SCOPE_AGENT);
  }

  // ---------------- epilogue: y = h_last @ Wd + bd --------------------------
  if (wg < 32) {
    const int mgy = wg >> 2;
    if (tid < 128) {
      uint32_t* f = &prod2[mgy * 128 + tid];
      poll2(f, f, (uint32_t)Tq);
    }
    __syncthreads();
    float* lflat = &lds[0][0];     // reuse LDS: 4 rows x 512 f32 = 8 KB
    {
      const int r = tid >> 6, o = (tid & 63) * 8;
      const char* src = (const char*)(hfin + (size_t)(wg * 4 + r) * Hq + o);
      uint4 a, b;
      LD16(a, src, "0");
      LD16(b, src, "16");
      wait_vm0();
      *(uint4*)(lflat + r * 512 + o) = a;
      *(uint4*)(lflat + r * 512 + o + 4) = b;
    }
    __syncthreads();
    const int r = tid >> 6, j = tid & 63;
    const float* hr = lflat + r * 512;
    float acc = bd[j];
    #pragma unroll 8
    for (int k = 0; k < Hq; ++k)
      acc = fmaf(hr[k], Wd[(size_t)k * FUTq + j], acc);
    out[(wg * 4 + r) * FUTq + j] = acc;
  }
}

extern "C" void kernel_launch(void* const* d_in, const int* in_sizes, int n_in,
                              void* d_out, int out_size, void* d_ws, size_t ws_size,
                              hipStream_t stream) {
  (void)in_sizes; (void)n_in; (void)out_size; (void)ws_size;
  const float* x  = (const float*)d_in[0];
  const float* W  = (const float*)d_in[1];
  const float* U  = (const float*)d_in[2];
  const float* b  = (const float*)d_in[3];
  const float* Wd = (const float*)d_in[4];
  const float* bd = (const float*)d_in[5];

  unsigned short* hbase = (unsigned short*)d_ws;                 // 512 KB
  uint32_t* prod2 = (uint32_t*)((char*)d_ws + 524288);           // 4 KB
  float*    hfin  = (float*)((char*)d_ws + 528384);              // 256 KB

  // zero h parity buffers + flags (h_0 = 0, flags = 0)
  hipMemsetAsync(d_ws, 0, 528384, stream);

  hipLaunchKernelGGL(lstm_persist, dim3(256), dim3(256), 0, stream,
                     x, W, U, b, Wd, bd, hbase, prod2, hfin, (float*)d_out);
}

// Round 7
// 3912.261 us; speedup vs baseline: 2.5064x; 1.3581x over previous
//
#include <hip/hip_runtime.h>
#include <stdint.h>

// Problem constants
#define Bq   128
#define Tq   512
#define Fq   64
#define Hq   512
#define G4q  2048
#define FUTq 64

// 256 WGs = 8 row-groups (mg) x 32 unit-groups (ng), 256 thr (4 waves).
// h exchanged as [parity][row][unit] u32 words (hi-bf16 | lo-bf16<<16):
//   - producer: lanes pack words -> LDS tile -> wave 0 stores FULL 64B lines
//     (sc0 sc1) -> vmcnt(0) -> one flag per WG.
//   - consumer: 32x dwordx4 sc0 sc1 loads, v_perm repack to hi/lo A-frags.
// U resident in registers as hi/lo bf16 B-fragments. No fences,
// no cache-maintenance; flags are relaxed agent atomics (proven visible).

typedef __attribute__((ext_vector_type(8))) short bfrag_t;
typedef __attribute__((ext_vector_type(4))) float accf_t;
typedef __attribute__((ext_vector_type(4))) float f4_t;
typedef __attribute__((ext_vector_type(4))) unsigned int u32x4;  // asm-safe 128b payload

static __device__ __forceinline__ accf_t mfma16(uint4 a, uint4 b, accf_t acc) {
  return __builtin_amdgcn_mfma_f32_16x16x32_bf16(
      __builtin_bit_cast(bfrag_t, a), __builtin_bit_cast(bfrag_t, b), acc, 0, 0, 0);
}

static __device__ __forceinline__ void pack2(float f0, float f1, uint32_t& h, uint32_t& l) {
  uint32_t b0 = __float_as_uint(f0), b1 = __float_as_uint(f1);
  h = (b0 >> 16) | (b1 & 0xffff0000u);
  float r0 = f0 - __uint_as_float(b0 & 0xffff0000u);
  float r1 = f1 - __uint_as_float(b1 & 0xffff0000u);
  l = (__float_as_uint(r0) >> 16) | (__float_as_uint(r1) & 0xffff0000u);
}

static __device__ __forceinline__ float sigmoidf_(float v) {
  return __fdividef(1.0f, 1.0f + __expf(-v));
}

// coherence-point 16B ops with compile-time byte offset
#define LD16(dst, base, IMM)                                                \
  asm volatile("global_load_dwordx4 %0, %1, off offset:" IMM " sc0 sc1"     \
               : "=v"(dst) : "v"(base) : "memory")
static __device__ __forceinline__ void st16_cc(void* p, u32x4 v) {
  asm volatile("global_store_dwordx4 %0, %1, off sc0 sc1" :: "v"(p), "v"(v) : "memory");
}
static __device__ __forceinline__ void stf_cc(void* p, float v) {
  asm volatile("global_store_dword %0, %1, off sc0 sc1" :: "v"(p), "v"(v) : "memory");
}
static __device__ __forceinline__ void wait_vm0() {
  asm volatile("s_waitcnt vmcnt(0)" ::: "memory");
  __builtin_amdgcn_sched_barrier(0);
}

static __device__ __forceinline__ void poll1(uint32_t* f, uint32_t tgt) {
  int guard = 0;
  while (__hip_atomic_load(f, __ATOMIC_RELAXED, __HIP_MEMORY_SCOPE_AGENT) < tgt) {
    __builtin_amdgcn_s_sleep(1);
    if (++guard > (1 << 23)) return;  // anti-hang; broken run fails validation
  }
}

__global__ __launch_bounds__(256, 1) void lstm_persist(
    const float* __restrict__ x, const float* __restrict__ W,
    const float* __restrict__ U, const float* __restrict__ bias_v,
    const float* __restrict__ Wd, const float* __restrict__ bd,
    uint32_t* __restrict__ hbuf,          // [2][128][512] u32 (hi | lo<<16)
    uint32_t* __restrict__ prod,          // [8][32] per-WG flags
    float* __restrict__ hfin,             // [128][512] final h fp32
    float* __restrict__ out)
{
  const int wg  = blockIdx.x;
  const int mg  = wg >> 5;
  const int ng  = wg & 31;
  const int tid = threadIdx.x;
  const int wv  = tid >> 6;
  const int l   = tid & 63;
  const int c   = l & 15;
  const int h4  = l >> 4;
  const int gate = c & 3;
  const int unit = ng * 16 + wv * 4 + (c >> 2);
  const int srccol = gate * 512 + unit;

  __shared__ float lds[128][65];
  __shared__ uint32_t stg[2][16][16];   // [parity][row16][unit16]

  // ---------------- stage U into B-fragment registers (hi/lo bf16) ----------
  uint4 Bhi[16], Blo[16];
  const int srow = tid >> 2, sg = tid & 3;
  #pragma unroll
  for (int tb = 0; tb < 4; ++tb) {
    __syncthreads();
    #pragma unroll
    for (int p = 0; p < 2; ++p) {
      const int kl = p * 64 + srow;
      const float* src = U + (size_t)(tb * 128 + kl) * G4q + sg * 512 + ng * 16;
      #pragma unroll
      for (int q = 0; q < 4; ++q) {
        f4_t vv = *(const f4_t*)(src + q * 4);
        #pragma unroll
        for (int e = 0; e < 4; ++e) {
          int uu = q * 4 + e;
          lds[kl][(uu >> 2) * 16 + (uu & 3) * 4 + sg] = vv[e];
        }
      }
    }
    __syncthreads();
    #pragma unroll
    for (int k2 = 0; k2 < 4; ++k2) {
      const int kk = tb * 4 + k2;
      uint32_t wh[4], wl[4];
      #pragma unroll
      for (int jp = 0; jp < 4; ++jp) {
        const int kloc = k2 * 32 + h4 * 8 + jp * 2;
        pack2(lds[kloc][wv * 16 + c], lds[kloc + 1][wv * 16 + c], wh[jp], wl[jp]);
      }
      Bhi[kk] = make_uint4(wh[0], wh[1], wh[2], wh[3]);
      Blo[kk] = make_uint4(wl[0], wl[1], wl[2], wl[3]);
    }
  }

  // ---------------- stage W the same way ------------------------------------
  uint4 Wh[2], Wl[2];
  __syncthreads();
  {
    const float* src = W + (size_t)srow * G4q + sg * 512 + ng * 16;
    #pragma unroll
    for (int q = 0; q < 4; ++q) {
      f4_t vv = *(const f4_t*)(src + q * 4);
      #pragma unroll
      for (int e = 0; e < 4; ++e) {
        int uu = q * 4 + e;
        lds[srow][(uu >> 2) * 16 + (uu & 3) * 4 + sg] = vv[e];
      }
    }
  }
  __syncthreads();
  #pragma unroll
  for (int kk = 0; kk < 2; ++kk) {
    uint32_t wh[4], wl[4];
    #pragma unroll
    for (int jp = 0; jp < 4; ++jp) {
      const int kloc = kk * 32 + h4 * 8 + jp * 2;
      pack2(lds[kloc][wv * 16 + c], lds[kloc + 1][wv * 16 + c], wh[jp], wl[jp]);
    }
    Wh[kk] = make_uint4(wh[0], wh[1], wh[2], wh[3]);
    Wl[kk] = make_uint4(wl[0], wl[1], wl[2], wl[3]);
  }
  __syncthreads();

  const float bval = bias_v[srccol];
  float cst[4] = {0.f, 0.f, 0.f, 0.f};

  const float* xrow = x + (size_t)(mg * 16 + c) * Tq * Fq + h4 * 8;
  const char*  hbb  = (const char*)hbuf;
  const size_t rowoff = (size_t)(mg * 16 + c) * 2048 + h4 * 32;
  uint32_t* fb = prod + mg * 32;

  // ---------------- recurrence ----------------------------------------------
  for (int t = 0; t < Tq; ++t) {
    const int pb = t & 1, pn = pb ^ 1;

    // x @ W for THIS step — no h dependency, overlap with the wait
    accf_t accA = {bval, bval, bval, bval};
    accf_t accB = {0.f, 0.f, 0.f, 0.f};
    accf_t accC = {0.f, 0.f, 0.f, 0.f};
    {
      const float* xp = xrow + (size_t)t * Fq;
      #pragma unroll
      for (int kk = 0; kk < 2; ++kk) {
        f4_t xa = *(const f4_t*)(xp + kk * 32);
        f4_t xb = *(const f4_t*)(xp + kk * 32 + 4);
        uint32_t xh[4], xl[4];
        pack2(xa[0], xa[1], xh[0], xl[0]);
        pack2(xa[2], xa[3], xh[1], xl[1]);
        pack2(xb[0], xb[1], xh[2], xl[2]);
        pack2(xb[2], xb[3], xh[3], xl[3]);
        uint4 XH = make_uint4(xh[0], xh[1], xh[2], xh[3]);
        uint4 XL = make_uint4(xl[0], xl[1], xl[2], xl[3]);
        accA = mfma16(XH, Wh[kk], accA);
        accB = mfma16(XL, Wh[kk], accB);
        accC = mfma16(XH, Wl[kk], accC);
      }
    }

    // wait: all 32 WGs of this row-group published step t-1 (ballot poll)
    {
      int guard = 0;
      for (;;) {
        uint32_t v = __hip_atomic_load(&fb[l & 31], __ATOMIC_RELAXED,
                                       __HIP_MEMORY_SCOPE_AGENT);
        if (!__ballot(v < (uint32_t)t)) break;
        __builtin_amdgcn_s_sleep(1);
        if (++guard > (1 << 23)) break;
      }
    }

    // issue all 32 h-loads (interleaved words, coherence-point reads)
    uint4 qa[32];
    const char* hp = hbb + (size_t)pb * 262144 + rowoff;
    LD16(qa[ 0], hp, "0");    LD16(qa[ 1], hp, "16");
    LD16(qa[ 2], hp, "128");  LD16(qa[ 3], hp, "144");
    LD16(qa[ 4], hp, "256");  LD16(qa[ 5], hp, "272");
    LD16(qa[ 6], hp, "384");  LD16(qa[ 7], hp, "400");
    LD16(qa[ 8], hp, "512");  LD16(qa[ 9], hp, "528");
    LD16(qa[10], hp, "640");  LD16(qa[11], hp, "656");
    LD16(qa[12], hp, "768");  LD16(qa[13], hp, "784");
    LD16(qa[14], hp, "896");  LD16(qa[15], hp, "912");
    LD16(qa[16], hp, "1024"); LD16(qa[17], hp, "1040");
    LD16(qa[18], hp, "1152"); LD16(qa[19], hp, "1168");
    LD16(qa[20], hp, "1280"); LD16(qa[21], hp, "1296");
    LD16(qa[22], hp, "1408"); LD16(qa[23], hp, "1424");
    LD16(qa[24], hp, "1536"); LD16(qa[25], hp, "1552");
    LD16(qa[26], hp, "1664"); LD16(qa[27], hp, "1680");
    LD16(qa[28], hp, "1792"); LD16(qa[29], hp, "1808");
    LD16(qa[30], hp, "1920"); LD16(qa[31], hp, "1936");
    wait_vm0();

    // repack (v_perm) + MFMA
    #pragma unroll
    for (int j = 0; j < 16; ++j) {
      uint4 a = qa[2 * j], b = qa[2 * j + 1];
      uint4 ahf, alf;
      ahf.x = __builtin_amdgcn_perm(a.y, a.x, 0x05040100u);
      ahf.y = __builtin_amdgcn_perm(a.w, a.z, 0x05040100u);
      ahf.z = __builtin_amdgcn_perm(b.y, b.x, 0x05040100u);
      ahf.w = __builtin_amdgcn_perm(b.w, b.z, 0x05040100u);
      alf.x = __builtin_amdgcn_perm(a.y, a.x, 0x07060302u);
      alf.y = __builtin_amdgcn_perm(a.w, a.z, 0x07060302u);
      alf.z = __builtin_amdgcn_perm(b.y, b.x, 0x07060302u);
      alf.w = __builtin_amdgcn_perm(b.w, b.z, 0x07060302u);
      accA = mfma16(ahf, Bhi[j], accA);
      accB = mfma16(alf, Bhi[j], accB);
      accC = mfma16(ahf, Blo[j], accC);
    }

    // gates + state update; pack word for (row = h4*4+gate, this unit)
    uint32_t word_out = 0;
    #pragma unroll
    for (int r = 0; r < 4; ++r) {
      float zr = accA[r] + accB[r] + accC[r];
      float s1 = __shfl_xor(zr, 1);
      float s2 = __shfl_xor(zr, 2);
      float s3 = __shfl_xor(zr, 3);
      const bool b0 = (gate & 1), b1 = (gate & 2);
      float t01a = b0 ? s1 : zr, t23a = b0 ? s3 : s2;
      float iv = b1 ? t23a : t01a;
      float gv = b1 ? t01a : t23a;
      float t01b = b0 ? zr : s1, t23b = b0 ? s2 : s3;
      float fv = b1 ? t23b : t01b;
      float ov = b1 ? t01b : t23b;
      float si = sigmoidf_(iv);
      float sf = sigmoidf_(fv);
      float so = sigmoidf_(ov);
      float cn = sf * cst[r] + si * fmaxf(gv, 0.f);
      cst[r] = cn;
      float hn = so * fmaxf(cn, 0.f);

      uint32_t hb = __float_as_uint(hn);
      uint32_t hi16 = hb >> 16;
      float res = hn - __uint_as_float(hb & 0xffff0000u);
      uint32_t lo16 = __float_as_uint(res) >> 16;
      uint32_t word = hi16 | (lo16 << 16);
      if (gate == r) word_out = word;
      if (t == Tq - 1 && gate == r)
        stf_cc(hfin + (size_t)(mg * 16 + h4 * 4 + r) * Hq + unit, hn);
    }
    stg[pb][h4 * 4 + gate][wv * 4 + (c >> 2)] = word_out;

    if (t == Tq - 1) wait_vm0();   // drain hfin stores before final flag
    __syncthreads();

    // wave 0: coalesced full-line publish + flag
    if (wv == 0) {
      u32x4 v = *(const u32x4*)&stg[pb][l >> 2][(l & 3) * 4];
      char* sp = (char*)hbuf + (size_t)pn * 262144 +
                 (size_t)(mg * 16 + (l >> 2)) * 2048 + ng * 64 + (l & 3) * 16;
      st16_cc(sp, v);
      asm volatile("s_waitcnt vmcnt(0)" ::: "memory");
      if (l == 0)
        __hip_atomic_store(&prod[mg * 32 + ng], (uint32_t)(t + 1),
                           __ATOMIC_RELAXED, __HIP_MEMORY_SCOPE_AGENT);
    }
  }

  // ---------------- epilogue: y = h_last @ Wd + bd --------------------------
  if (wg < 32) {
    const int mgy = wg >> 2;
    if (tid < 32) poll1(&prod[mgy * 32 + tid], (uint32_t)Tq);
    __syncthreads();
    float* lflat = &lds[0][0];
    {
      const int r = tid >> 6, o = (tid & 63) * 8;
      const char* src = (const char*)(hfin + (size_t)(wg * 4 + r) * Hq + o);
      uint4 a, b;
      LD16(a, src, "0");
      LD16(b, src, "16");
      wait_vm0();
      *(uint4*)(lflat + r * 512 + o) = a;
      *(uint4*)(lflat + r * 512 + o + 4) = b;
    }
    __syncthreads();
    const int r = tid >> 6, j = tid & 63;
    const float* hr = lflat + r * 512;
    float acc = bd[j];
    #pragma unroll 8
    for (int k = 0; k < Hq; ++k)
      acc = fmaf(hr[k], Wd[(size_t)k * FUTq + j], acc);
    out[(wg * 4 + r) * FUTq + j] = acc;
  }
}

extern "C" void kernel_launch(void* const* d_in, const int* in_sizes, int n_in,
                              void* d_out, int out_size, void* d_ws, size_t ws_size,
                              hipStream_t stream) {
  (void)in_sizes; (void)n_in; (void)out_size; (void)ws_size;
  const float* x  = (const float*)d_in[0];
  const float* W  = (const float*)d_in[1];
  const float* U  = (const float*)d_in[2];
  const float* b  = (const float*)d_in[3];
  const float* Wd = (const float*)d_in[4];
  const float* bd = (const float*)d_in[5];

  uint32_t* hbuf = (uint32_t*)d_ws;                          // 512 KB
  uint32_t* prod = (uint32_t*)((char*)d_ws + 524288);        // 1 KB
  float*    hfin = (float*)((char*)d_ws + 528384);           // 256 KB

  // zero h parity buffers + flags (h_0 = 0, flags = 0)
  (void)hipMemsetAsync(d_ws, 0, 525312, stream);

  hipLaunchKernelGGL(lstm_persist, dim3(256), dim3(256), 0, stream,
                     x, W, U, b, Wd, bd, hbuf, prod, hfin, (float*)d_out);
}

// Round 8
// 2215.479 us; speedup vs baseline: 4.4261x; 1.7659x over previous
//
#include <hip/hip_runtime.h>
#include <stdint.h>

// Problem constants
#define Bq   128
#define Tq   512
#define Fq   64
#define Hq   512
#define G4q  2048
#define FUTq 64

// 256 WGs = 8 row-groups (mg = wg&7 -> XCD-local gang if round-robin holds)
//           x 32 unit-groups (ng = wg>>3), 256 thr (4 waves).
// h exchanged as [parity][row][unit] u32 (hi-bf16 | lo-bf16<<16), full 64B lines.
// Per step: wave0 polls gang flags; wave1 publishes (store+vmcnt+flag) the
// PREVIOUS step's h concurrently; waves split the 32 h-line loads 4-way and
// share MFMA A-fragments through LDS. U resident in registers as hi/lo bf16
// B-fragments. No fences / cache maintenance; relaxed agent-scope flags.

typedef __attribute__((ext_vector_type(8))) short bfrag_t;
typedef __attribute__((ext_vector_type(4))) float accf_t;
typedef __attribute__((ext_vector_type(4))) float f4_t;
typedef __attribute__((ext_vector_type(4))) unsigned int u32x4;  // asm-safe 128b payload

static __device__ __forceinline__ accf_t mfma16(uint4 a, uint4 b, accf_t acc) {
  return __builtin_amdgcn_mfma_f32_16x16x32_bf16(
      __builtin_bit_cast(bfrag_t, a), __builtin_bit_cast(bfrag_t, b), acc, 0, 0, 0);
}

static __device__ __forceinline__ void pack2(float f0, float f1, uint32_t& h, uint32_t& l) {
  uint32_t b0 = __float_as_uint(f0), b1 = __float_as_uint(f1);
  h = (b0 >> 16) | (b1 & 0xffff0000u);
  float r0 = f0 - __uint_as_float(b0 & 0xffff0000u);
  float r1 = f1 - __uint_as_float(b1 & 0xffff0000u);
  l = (__float_as_uint(r0) >> 16) | (__float_as_uint(r1) & 0xffff0000u);
}

static __device__ __forceinline__ float sigmoidf_(float v) {
  return __fdividef(1.0f, 1.0f + __expf(-v));
}

// coherence-point 16B ops with compile-time byte offset
#define LD16(dst, base, IMM)                                                \
  asm volatile("global_load_dwordx4 %0, %1, off offset:" IMM " sc0 sc1"     \
               : "=v"(dst) : "v"(base) : "memory")
static __device__ __forceinline__ void st16_cc(void* p, u32x4 v) {
  asm volatile("global_store_dwordx4 %0, %1, off sc0 sc1" :: "v"(p), "v"(v) : "memory");
}
static __device__ __forceinline__ void stf_cc(void* p, float v) {
  asm volatile("global_store_dword %0, %1, off sc0 sc1" :: "v"(p), "v"(v) : "memory");
}
static __device__ __forceinline__ void wait_vm0() {
  asm volatile("s_waitcnt vmcnt(0)" ::: "memory");
  __builtin_amdgcn_sched_barrier(0);
}

static __device__ __forceinline__ void poll1(uint32_t* f, uint32_t tgt) {
  int guard = 0;
  while (__hip_atomic_load(f, __ATOMIC_RELAXED, __HIP_MEMORY_SCOPE_AGENT) < tgt) {
    __builtin_amdgcn_s_sleep(1);
    if (++guard > (1 << 23)) return;  // anti-hang; broken run fails validation
  }
}

__global__ __launch_bounds__(256, 1) void lstm_persist(
    const float* __restrict__ x, const float* __restrict__ W,
    const float* __restrict__ U, const float* __restrict__ bias_v,
    const float* __restrict__ Wd, const float* __restrict__ bd,
    uint32_t* __restrict__ hbuf,          // [2][128][512] u32 (hi | lo<<16)
    uint32_t* __restrict__ prod,          // [8][32] per-WG flags
    float* __restrict__ hfin,             // [128][512] final h fp32
    float* __restrict__ out)
{
  const int wg  = blockIdx.x;
  const int mg  = wg & 7;                 // XCD-local gang (if %8 round-robin)
  const int ng  = wg >> 3;
  const int tid = threadIdx.x;
  const int wv  = tid >> 6;
  const int l   = tid & 63;
  const int c   = l & 15;
  const int h4  = l >> 4;
  const int gate = c & 3;
  const int unit = ng * 16 + wv * 4 + (c >> 2);
  const int srccol = gate * 512 + unit;

  __shared__ float lds[128][65];
  __shared__ uint32_t stg[2][16][16];     // [parity][row16][unit16]
  __shared__ uint4 fragH[16 * 64];        // per-K-slice hi A-frags, [j][lane]
  __shared__ uint4 fragL[16 * 64];        // per-K-slice lo A-frags

  // ---------------- stage U into B-fragment registers (hi/lo bf16) ----------
  uint4 Bhi[16], Blo[16];
  const int srow = tid >> 2, sg = tid & 3;
  #pragma unroll
  for (int tb = 0; tb < 4; ++tb) {
    __syncthreads();
    #pragma unroll
    for (int p = 0; p < 2; ++p) {
      const int kl = p * 64 + srow;
      const float* src = U + (size_t)(tb * 128 + kl) * G4q + sg * 512 + ng * 16;
      #pragma unroll
      for (int q = 0; q < 4; ++q) {
        f4_t vv = *(const f4_t*)(src + q * 4);
        #pragma unroll
        for (int e = 0; e < 4; ++e) {
          int uu = q * 4 + e;
          lds[kl][(uu >> 2) * 16 + (uu & 3) * 4 + sg] = vv[e];
        }
      }
    }
    __syncthreads();
    #pragma unroll
    for (int k2 = 0; k2 < 4; ++k2) {
      const int kk = tb * 4 + k2;
      uint32_t wh[4], wl[4];
      #pragma unroll
      for (int jp = 0; jp < 4; ++jp) {
        const int kloc = k2 * 32 + h4 * 8 + jp * 2;
        pack2(lds[kloc][wv * 16 + c], lds[kloc + 1][wv * 16 + c], wh[jp], wl[jp]);
      }
      Bhi[kk] = make_uint4(wh[0], wh[1], wh[2], wh[3]);
      Blo[kk] = make_uint4(wl[0], wl[1], wl[2], wl[3]);
    }
  }

  // ---------------- stage W the same way ------------------------------------
  uint4 Wh[2], Wl[2];
  __syncthreads();
  {
    const float* src = W + (size_t)srow * G4q + sg * 512 + ng * 16;
    #pragma unroll
    for (int q = 0; q < 4; ++q) {
      f4_t vv = *(const f4_t*)(src + q * 4);
      #pragma unroll
      for (int e = 0; e < 4; ++e) {
        int uu = q * 4 + e;
        lds[srow][(uu >> 2) * 16 + (uu & 3) * 4 + sg] = vv[e];
      }
    }
  }
  __syncthreads();
  #pragma unroll
  for (int kk = 0; kk < 2; ++kk) {
    uint32_t wh[4], wl[4];
    #pragma unroll
    for (int jp = 0; jp < 4; ++jp) {
      const int kloc = kk * 32 + h4 * 8 + jp * 2;
      pack2(lds[kloc][wv * 16 + c], lds[kloc + 1][wv * 16 + c], wh[jp], wl[jp]);
    }
    Wh[kk] = make_uint4(wh[0], wh[1], wh[2], wh[3]);
    Wl[kk] = make_uint4(wl[0], wl[1], wl[2], wl[3]);
  }
  __syncthreads();

  const float bval = bias_v[srccol];
  float cst[4] = {0.f, 0.f, 0.f, 0.f};

  const float* xrow = x + (size_t)(mg * 16 + c) * Tq * Fq + h4 * 8;
  const char*  hbb  = (const char*)hbuf;
  const size_t rowoff = (size_t)(mg * 16 + c) * 2048 + h4 * 32;
  uint32_t* fb = prod + mg * 32;

  // ---------------- recurrence ----------------------------------------------
  for (int t = 0; t < Tq; ++t) {
    const int pb = t & 1;

    // phase 1 (all waves): x @ W — no h dependency, overlaps poll/publish
    accf_t accA = {bval, bval, bval, bval};
    accf_t accB = {0.f, 0.f, 0.f, 0.f};
    accf_t accC = {0.f, 0.f, 0.f, 0.f};
    {
      const float* xp = xrow + (size_t)t * Fq;
      #pragma unroll
      for (int kk = 0; kk < 2; ++kk) {
        f4_t xa = *(const f4_t*)(xp + kk * 32);
        f4_t xb = *(const f4_t*)(xp + kk * 32 + 4);
        uint32_t xh[4], xl[4];
        pack2(xa[0], xa[1], xh[0], xl[0]);
        pack2(xa[2], xa[3], xh[1], xl[1]);
        pack2(xb[0], xb[1], xh[2], xl[2]);
        pack2(xb[2], xb[3], xh[3], xl[3]);
        uint4 XH = make_uint4(xh[0], xh[1], xh[2], xh[3]);
        uint4 XL = make_uint4(xl[0], xl[1], xl[2], xl[3]);
        accA = mfma16(XH, Wh[kk], accA);
        accB = mfma16(XL, Wh[kk], accB);
        accC = mfma16(XH, Wl[kk], accC);
      }
    }

    // phase 2: wave 0 alone polls the 32 gang flags (>= t)
    if (wv == 0) {
      int guard = 0;
      for (;;) {
        uint32_t v = __hip_atomic_load(&fb[l & 31], __ATOMIC_RELAXED,
                                       __HIP_MEMORY_SCOPE_AGENT);
        if (!__ballot(v < (uint32_t)t)) break;
        __builtin_amdgcn_s_sleep(1);
        if (++guard > (1 << 23)) break;
      }
    }
    __syncthreads();   // barrier B: release all waves to load

    // phase 3: wave wv loads its 4 K-slices (8 x 16B), perms, shares via LDS
    {
      const char* hp2 = hbb + (size_t)pb * 262144 + rowoff + wv * 512;
      uint4 q0, q1, q2, q3, q4, q5, q6, q7;
      LD16(q0, hp2, "0");   LD16(q1, hp2, "16");
      LD16(q2, hp2, "128"); LD16(q3, hp2, "144");
      LD16(q4, hp2, "256"); LD16(q5, hp2, "272");
      LD16(q6, hp2, "384"); LD16(q7, hp2, "400");
      wait_vm0();
      uint4 qs[8] = {q0, q1, q2, q3, q4, q5, q6, q7};
      #pragma unroll
      for (int jj = 0; jj < 4; ++jj) {
        uint4 a = qs[2 * jj], b = qs[2 * jj + 1];
        uint4 ahf, alf;
        ahf.x = __builtin_amdgcn_perm(a.y, a.x, 0x05040100u);
        ahf.y = __builtin_amdgcn_perm(a.w, a.z, 0x05040100u);
        ahf.z = __builtin_amdgcn_perm(b.y, b.x, 0x05040100u);
        ahf.w = __builtin_amdgcn_perm(b.w, b.z, 0x05040100u);
        alf.x = __builtin_amdgcn_perm(a.y, a.x, 0x07060302u);
        alf.y = __builtin_amdgcn_perm(a.w, a.z, 0x07060302u);
        alf.z = __builtin_amdgcn_perm(b.y, b.x, 0x07060302u);
        alf.w = __builtin_amdgcn_perm(b.w, b.z, 0x07060302u);
        fragH[(wv * 4 + jj) * 64 + l] = ahf;
        fragL[(wv * 4 + jj) * 64 + l] = alf;
      }
    }
    __syncthreads();   // barrier C: frags visible to all waves

    // phase 4: MFMA over all 16 K-slices from LDS
    #pragma unroll
    for (int j = 0; j < 16; ++j) {
      uint4 ah = fragH[j * 64 + l];
      uint4 al = fragL[j * 64 + l];
      accA = mfma16(ah, Bhi[j], accA);
      accB = mfma16(al, Bhi[j], accB);
      accC = mfma16(ah, Blo[j], accC);
    }

    // phase 5: gates + state update; pack word for (row = h4*4+gate, unit)
    uint32_t word_out = 0;
    #pragma unroll
    for (int r = 0; r < 4; ++r) {
      float zr = accA[r] + accB[r] + accC[r];
      float s1 = __shfl_xor(zr, 1);
      float s2 = __shfl_xor(zr, 2);
      float s3 = __shfl_xor(zr, 3);
      const bool b0 = (gate & 1), b1 = (gate & 2);
      float t01a = b0 ? s1 : zr, t23a = b0 ? s3 : s2;
      float iv = b1 ? t23a : t01a;
      float gv = b1 ? t01a : t23a;
      float t01b = b0 ? zr : s1, t23b = b0 ? s2 : s3;
      float fv = b1 ? t23b : t01b;
      float ov = b1 ? t01b : t23b;
      float si = sigmoidf_(iv);
      float sf = sigmoidf_(fv);
      float so = sigmoidf_(ov);
      float cn = sf * cst[r] + si * fmaxf(gv, 0.f);
      cst[r] = cn;
      float hn = so * fmaxf(cn, 0.f);

      uint32_t hb = __float_as_uint(hn);
      uint32_t hi16 = hb >> 16;
      float res = hn - __uint_as_float(hb & 0xffff0000u);
      uint32_t lo16 = __float_as_uint(res) >> 16;
      uint32_t word = hi16 | (lo16 << 16);
      if (gate == r) word_out = word;
      if (t == Tq - 1 && gate == r)
        stf_cc(hfin + (size_t)(mg * 16 + h4 * 4 + r) * Hq + unit, hn);
    }
    stg[pb][h4 * 4 + gate][wv * 4 + (c >> 2)] = word_out;

    if (t == Tq - 1) wait_vm0();   // drain hfin stores before final flag
    __syncthreads();   // barrier D: stg tile complete

    // phase 6: wave 1 publishes full lines + flag (overlaps next poll)
    if (wv == 1) {
      const int pn = pb ^ 1;
      u32x4 v = *(const u32x4*)&stg[pb][l >> 2][(l & 3) * 4];
      char* sp = (char*)hbuf + (size_t)pn * 262144 +
                 (size_t)(mg * 16 + (l >> 2)) * 2048 + ng * 64 + (l & 3) * 16;
      st16_cc(sp, v);
      asm volatile("s_waitcnt vmcnt(0)" ::: "memory");
      if (l == 0)
        __hip_atomic_store(&prod[mg * 32 + ng], (uint32_t)(t + 1),
                           __ATOMIC_RELAXED, __HIP_MEMORY_SCOPE_AGENT);
    }
  }

  // ---------------- epilogue: y = h_last @ Wd + bd --------------------------
  if (wg < 32) {
    const int mgy = wg >> 2;
    if (tid < 32) poll1(&prod[mgy * 32 + tid], (uint32_t)Tq);
    __syncthreads();
    float* lflat = &lds[0][0];
    {
      const int r = tid >> 6, o = (tid & 63) * 8;
      const char* src = (const char*)(hfin + (size_t)(wg * 4 + r) * Hq + o);
      uint4 a, b;
      LD16(a, src, "0");
      LD16(b, src, "16");
      wait_vm0();
      *(uint4*)(lflat + r * 512 + o) = a;
      *(uint4*)(lflat + r * 512 + o + 4) = b;
    }
    __syncthreads();
    const int r = tid >> 6, j = tid & 63;
    const float* hr = lflat + r * 512;
    float acc = bd[j];
    #pragma unroll 8
    for (int k = 0; k < Hq; ++k)
      acc = fmaf(hr[k], Wd[(size_t)k * FUTq + j], acc);
    out[(wg * 4 + r) * FUTq + j] = acc;
  }
}

extern "C" void kernel_launch(void* const* d_in, const int* in_sizes, int n_in,
                              void* d_out, int out_size, void* d_ws, size_t ws_size,
                              hipStream_t stream) {
  (void)in_sizes; (void)n_in; (void)out_size; (void)ws_size;
  const float* x  = (const float*)d_in[0];
  const float* W  = (const float*)d_in[1];
  const float* U  = (const float*)d_in[2];
  const float* b  = (const float*)d_in[3];
  const float* Wd = (const float*)d_in[4];
  const float* bd = (const float*)d_in[5];

  uint32_t* hbuf = (uint32_t*)d_ws;                          // 512 KB
  uint32_t* prod = (uint32_t*)((char*)d_ws + 524288);        // 1 KB
  float*    hfin = (float*)((char*)d_ws + 528384);           // 256 KB

  // zero h parity buffers + flags (h_0 = 0, flags = 0)
  (void)hipMemsetAsync(d_ws, 0, 525312, stream);

  hipLaunchKernelGGL(lstm_persist, dim3(256), dim3(256), 0, stream,
                     x, W, U, b, Wd, bd, hbuf, prod, hfin, (float*)d_out);
}